// Round 6
// baseline (8037.315 us; speedup 1.0000x reference)
//
#include <hip/hip_runtime.h>
#include <math.h>

// ---------------------------------------------------------------------------
// 4-layer LSTM, B=64 T=512 D=H=1024. Persistent cooperative kernel, wavefront
// schedule (layer l works on t = s - l). Round-6 structure:
//   - Wave role = {mat(2) x kquarter(4)}. Each wave: all 4 gates x 16 cols
//     over K=256. Weights bw[4][8] half8 = 128 VGPR (same budget as r5).
//     Every A-fragment is consumed by exactly ONE wave -> A loaded directly
//     global->VGPR (L2-resident). NO LDS staging, no K-loop syncthreads.
//   - Deterministic partial-K reduction: zpl[4 kq][64 v][64 b] f32 (64 KB),
//     b-index XOR-swizzled by v-parity (b ^= (v&1)<<4) so f32x4 plane
//     accesses are bank-conflict-free. mat0 writes, sync, mat1 accumulates,
//     sync, gate threads sum the 4 planes.
//   - Single-hop all-poll grid barrier: each block posts flags[blk]=tgt
//     (relaxed agent); 256 threads poll all 256 flags in parallel; after all
//     polls complete (syncthreads) one acquire fence, then syncthreads.
// Unchanged (r5-verified): relaxed-agent store/poll coherence discipline,
// MFMA fragment conventions, fp32 gate math, h16 double-buffer parity,
// c-state in registers.
// ---------------------------------------------------------------------------

#define BSZ 64
#define TSZ 512
#define DSZ 1024
#define HSZ 1024
#define LSZ 4
#define NBLK 256
#define NTHR 512
#define NSTEP (TSZ + LSZ - 1)   // 515

typedef _Float16 half8  __attribute__((ext_vector_type(8)));
typedef _Float16 half4  __attribute__((ext_vector_type(4)));
typedef _Float16 half2v __attribute__((ext_vector_type(2)));
typedef float    f32x4  __attribute__((ext_vector_type(4)));
typedef float    f32x8  __attribute__((ext_vector_type(8)));

// workspace layout (bytes)
constexpr size_t N_X  = (size_t)BSZ * TSZ * DSZ;       // halfs
constexpr size_t N_H  = (size_t)2 * LSZ * BSZ * HSZ;   // halfs (h double buffer)
constexpr size_t OFF_X     = 0;
constexpr size_t OFF_H     = OFF_X + N_X * 2;
constexpr size_t OFF_FLAGS = OFF_H + N_H * 2;          // 256 flags, 64B apart
constexpr size_t BAR_BYTES = (size_t)NBLK * 64;

__device__ inline float sigmoidf_(float x) { return 1.0f / (1.0f + expf(-x)); }

// Single-hop all-poll grid barrier (tgt strictly increasing).
// Entry syncthreads drains this block's global stores (vmcnt(0) before
// s_barrier). Post own flag; 256 threads poll the 256 flags in parallel
// (relaxed agent loads — no cache maintenance per poll, r5-verified).
// After ALL polls complete (syncthreads), one acquire fence invalidates
// stale L1/L2 so subsequent reads see every producer's data; final
// syncthreads orders the fence before any data read.
__device__ inline void gbar(unsigned* flags, unsigned tgt) {
  __syncthreads();
  const int t = threadIdx.x;
  if (t == 0)
    __hip_atomic_store(&flags[(size_t)blockIdx.x * 16], tgt, __ATOMIC_RELAXED,
                       __HIP_MEMORY_SCOPE_AGENT);
  if (t < NBLK) {
    while (__hip_atomic_load(&flags[(size_t)t * 16], __ATOMIC_RELAXED,
                             __HIP_MEMORY_SCOPE_AGENT) < tgt)
      __builtin_amdgcn_s_sleep(2);
  }
  __syncthreads();
  if (t == 0) __builtin_amdgcn_fence(__ATOMIC_ACQUIRE, "agent");
  __syncthreads();
}

__global__ __launch_bounds__(NTHR, 2) void lstm_persistent(
    const float* __restrict__ xin, const float* __restrict__ Wih,
    const float* __restrict__ Whh, const float* __restrict__ bih,
    const float* __restrict__ bhh, float* __restrict__ out,
    char* __restrict__ ws)
{
  _Float16* x16   = (_Float16*)(ws + OFF_X);
  _Float16* h16   = (_Float16*)(ws + OFF_H);
  unsigned* flags = (unsigned*)(ws + OFF_FLAGS);

  const int tid  = threadIdx.x;
  const int gtid = blockIdx.x * NTHR + tid;
  const int lane = tid & 63;
  const int w    = tid >> 6;        // wave 0..7
  const int mat  = w >> 2;          // 0 = input-side, 1 = recurrent
  const int kq   = w & 3;           // K-quarter (256 k's)
  const int ln15 = lane & 15;
  const int lq   = lane >> 4;

  const int l  = blockIdx.x >> 6;   // layer
  const int cc = blockIdx.x & 63;   // column chunk (16 H-cols)
  const int c0 = cc * 16;

  // ---- weight preload into registers (fp32 -> fp16, one time) ----
  // B-frag (r3/r5-verified): lane holds W[row = gate g, col c0+ln15] at
  // k = kq*256 + ks*32 + lq*8 + 0..7.
  const float* Wsel = mat ? Whh : Wih;
  half8 bw[4][8];
#pragma unroll
  for (int g = 0; g < 4; ++g) {
    const int grow = l * 4096 + g * 1024 + c0 + ln15;
    const float* wrow = Wsel + (size_t)grow * 1024 + kq * 256;
#pragma unroll
    for (int ks = 0; ks < 8; ++ks) {
      f32x8 f = *(const f32x8*)(wrow + ks * 32 + lq * 8);
      bw[g][ks] = __builtin_convertvector(f, half8);
    }
  }

  // ---- gate-math ownership: batch row gb, column pair gc/gc+1 ----
  const int gb = tid & 63;            // batch row
  const int gc = (tid >> 6) * 2;      // even col 0..14
  float bsg[4][2];
#pragma unroll
  for (int g = 0; g < 4; ++g) {
    const int bb = l * 4096 + g * 1024 + c0 + gc;
    bsg[g][0] = bih[bb] + bhh[bb];
    bsg[g][1] = bih[bb + 1] + bhh[bb + 1];
  }
  float cr0 = 0.f, cr1 = 0.f;         // block-private c-state (registers)

  // ---- pre-phase: cast x to fp16, zero h — relaxed agent stores ----
  {
    const f32x4* s4 = (const f32x4*)xin;
    unsigned long long* xu = (unsigned long long*)x16;
    for (int i = gtid; i < (int)(N_X / 4); i += NBLK * NTHR) {
      half4 v = __builtin_convertvector(s4[i], half4);
      __hip_atomic_store(&xu[i], __builtin_bit_cast(unsigned long long, v),
                         __ATOMIC_RELAXED, __HIP_MEMORY_SCOPE_AGENT);
    }
    unsigned long long* hz = (unsigned long long*)h16;
    for (int i = gtid; i < (int)(N_H / 4); i += NBLK * NTHR)
      __hip_atomic_store(&hz[i], 0ull, __ATOMIC_RELAXED,
                         __HIP_MEMORY_SCOPE_AGENT);
  }
  unsigned btgt = 1;
  gbar(flags, btgt++);

  // ---- LDS: partial-z planes only (exactly 64 KB) ----
  // zpl[kq][v][b'] f32, v = gate-row (g*16+col), b' = b ^ ((v&1)<<4).
  __shared__ __align__(16) float zpl[4 * 64 * 64];

  const int lm1 = (l > 0) ? (l - 1) : 0;

  for (int s = 0; s < NSTEP; ++s) {
    const int t = s - l;
    if (t >= 0 && t < TSZ) {
      const int prevslot = (s + 1) & 1;
      const _Float16* hin  = h16 + (size_t)prevslot * (LSZ * BSZ * HSZ) +
                             (size_t)lm1 * (BSZ * HSZ);
      const _Float16* hown = h16 + (size_t)prevslot * (LSZ * BSZ * HSZ) +
                             (size_t)l * (BSZ * HSZ);

      // wave-uniform activation base + per-lane 32-bit element offsets
      const _Float16* bm;
      int stride;
      if (mat == 0) {
        if (l == 0) { bm = x16 + (size_t)t * DSZ; stride = TSZ * DSZ; }
        else        { bm = hin;                   stride = HSZ; }
      } else        { bm = hown;                  stride = HSZ; }
      int off[4];
#pragma unroll
      for (int mt = 0; mt < 4; ++mt)
        off[mt] = (mt * 16 + ln15) * stride + kq * 256 + lq * 8;

      // ---- MFMA phase: A direct from global (L2), B from registers ----
      f32x4 acc[4][4] = {};   // [mt][g]
#pragma unroll
      for (int ks = 0; ks < 8; ++ks) {
        half8 a[4];
#pragma unroll
        for (int mt = 0; mt < 4; ++mt)
          a[mt] = *(const half8*)(bm + off[mt] + ks * 32);
#pragma unroll
        for (int g = 0; g < 4; ++g)
#pragma unroll
          for (int mt = 0; mt < 4; ++mt)
            acc[mt][g] = __builtin_amdgcn_mfma_f32_16x16x32_f16(
                a[mt], bw[g][ks], acc[mt][g], 0, 0, 0);
      }

      // ---- deterministic 2-pass reduction over kq via planes ----
      // plane idx: kq*4096 + v*64 + (b ^ ((v&1)<<4)); v = g*16+ln15,
      // b = mt*16+lq*4 (f32x4 spans r=0..3). C/D map (r3-verified):
      // C row = batch = mt*16+lq*4+r, C col = gate-row = g*16+ln15.
      if (mat == 0) {
#pragma unroll
        for (int mt = 0; mt < 4; ++mt)
#pragma unroll
          for (int g = 0; g < 4; ++g) {
            const int v  = g * 16 + ln15;
            const int bp = (mt * 16 + lq * 4) ^ ((ln15 & 1) << 4);
            *(f32x4*)&zpl[kq * 4096 + v * 64 + bp] = acc[mt][g];
          }
      }
      __syncthreads();
      if (mat == 1) {
#pragma unroll
        for (int mt = 0; mt < 4; ++mt)
#pragma unroll
          for (int g = 0; g < 4; ++g) {
            const int v  = g * 16 + ln15;
            const int bp = (mt * 16 + lq * 4) ^ ((ln15 & 1) << 4);
            f32x4* p = (f32x4*)&zpl[kq * 4096 + v * 64 + bp];
            *p = *p + acc[mt][g];
          }
      }
      __syncthreads();

      // ---- gate math (fp32): thread owns (gb, cols gc/gc+1) ----
      {
        float z[4][2];
#pragma unroll
        for (int g = 0; g < 4; ++g)
#pragma unroll
          for (int j = 0; j < 2; ++j) {
            const int v  = g * 16 + gc + j;
            const int bp = gb ^ ((v & 1) << 4);
            float sum = zpl[0 * 4096 + v * 64 + bp] +
                        zpl[1 * 4096 + v * 64 + bp] +
                        zpl[2 * 4096 + v * 64 + bp] +
                        zpl[3 * 4096 + v * 64 + bp];
            z[g][j] = sum + bsg[g][j];
          }
        float cn0 = sigmoidf_(z[1][0]) * cr0 +
                    sigmoidf_(z[0][0]) * tanhf(z[2][0]);
        float cn1 = sigmoidf_(z[1][1]) * cr1 +
                    sigmoidf_(z[0][1]) * tanhf(z[2][1]);
        float hn0 = sigmoidf_(z[3][0]) * tanhf(cn0);
        float hn1 = sigmoidf_(z[3][1]) * tanhf(cn1);
        cr0 = cn0; cr1 = cn1;
        half2v hv; hv[0] = (_Float16)hn0; hv[1] = (_Float16)hn1;
        const size_t ho = (size_t)(s & 1) * (LSZ * BSZ * HSZ) +
                          (size_t)l * (BSZ * HSZ) + (size_t)gb * HSZ + c0 + gc;
        __hip_atomic_store((unsigned*)(h16 + ho),
                           __builtin_bit_cast(unsigned, hv),
                           __ATOMIC_RELAXED, __HIP_MEMORY_SCOPE_AGENT);
        if (l == LSZ - 1 && t == TSZ - 1) {
          out[(size_t)gb * HSZ + c0 + gc]     = hn0;
          out[(size_t)gb * HSZ + c0 + gc + 1] = hn1;
        }
      }
    }
    gbar(flags, btgt++);
  }
}

extern "C" void kernel_launch(void* const* d_in, const int* in_sizes, int n_in,
                              void* d_out, int out_size, void* d_ws, size_t ws_size,
                              hipStream_t stream) {
  const float* x   = (const float*)d_in[0];
  const float* Wih = (const float*)d_in[1];
  const float* Whh = (const float*)d_in[2];
  const float* bih = (const float*)d_in[3];
  const float* bhh = (const float*)d_in[4];
  float* out = (float*)d_out;
  char*  ws  = (char*)d_ws;

  // barrier flags zeroed every call (captured in graph -> re-zeroed per replay)
  hipMemsetAsync(ws + OFF_FLAGS, 0, BAR_BYTES, stream);

  void* args[] = {(void*)&x, (void*)&Wih, (void*)&Whh, (void*)&bih,
                  (void*)&bhh, (void*)&out, (void*)&ws};
  hipLaunchCooperativeKernel((const void*)lstm_persistent, dim3(NBLK), dim3(NTHR),
                             args, 0, stream);
}